// Round 4
// baseline (6898.849 us; speedup 1.0000x reference)
//
#include <hip/hip_runtime.h>

typedef unsigned int u32;
typedef unsigned long long u64;
typedef unsigned char u8;

#define Bc 256
#define Tc 325
#define NSc 39
#define COc 64
#define NCc 20
#define ESc 117
#define ETc 648

// workspace layout in 4-byte units
#define WS_ROFF_S 0        // 40 ints
#define WS_EDGE_S 64       // 117 int2
#define WS_DINV_S 304      // 39 f
#define WS_ROFF_T 352      // 326 ints
#define WS_EDGE_T 680      // 648 int2
#define WS_DINV_T 1976     // 325 f
#define WS_WT     2304     // 416000 f  (tfc1_w transposed [20][20800])
#define WS_W1T    418304   // 49920 f   (fc1_w  transposed [20][2496])
#define WS_OUTS   468224   // 5120 f
#define WS_OUTT   473344   // 5120 f

// ---------------- prep: CSR (by dst, interleaved {src, nrm}) for both graphs ----------------
__global__ void prep_graph(const int* __restrict__ eiS, const int* __restrict__ eiT,
                           int* __restrict__ wsI, float* __restrict__ wsF) {
  const int which = blockIdx.x;
  const int* ei = which ? eiT : eiS;
  const int nE = which ? ETc : ESc;
  const int nN = which ? Tc : NSc;
  int* roff = wsI + (which ? WS_ROFF_T : WS_ROFF_S);
  int2* edge = (int2*)(wsI + (which ? WS_EDGE_T : WS_EDGE_S));
  float* dinv = wsF + (which ? WS_DINV_T : WS_DINV_S);
  const int* src = ei;
  const int* dst = ei + nE;
  for (int n = threadIdx.x; n < nN; n += blockDim.x) {
    int deg = 0, before = 0;
    for (int e = 0; e < nE; ++e) { deg += (dst[e] == n); before += (dst[e] < n); }
    roff[n] = before;
    if (n == nN - 1) roff[nN] = before + deg;
    dinv[n] = (deg > 0) ? (1.0f / sqrtf((float)deg)) : 0.0f;
  }
  __syncthreads();
  for (int n = threadIdx.x; n < nN; n += blockDim.x) {
    int cur = roff[n];
    float dn = dinv[n];
    for (int e = 0; e < nE; ++e) {
      if (dst[e] == n) {
        edge[cur] = make_int2(src[e], __float_as_int(dinv[src[e]] * dn));
        ++cur;
      }
    }
  }
}

// ---------------- prep: transpose both fc weights ----------------
__global__ void prep_w(const float* __restrict__ w2, float* __restrict__ wT,
                       const float* __restrict__ w1, float* __restrict__ w1T) {
  int i = blockIdx.x * 256 + threadIdx.x;
  if (i < NCc * Tc * COc) {
    int j = i / (Tc * COc);
    int p = i - j * (Tc * COc);
    wT[i] = w2[p * NCc + j];
  }
  if (i < NCc * NSc * COc) {
    int j = i / (NSc * COc);
    int p = i - j * (NSc * COc);
    w1T[i] = w1[p * NCc + j];
  }
}

// ---------------- spatial: 1 batch/block, 8 waves, fc weights register-resident ----------------
__global__ __launch_bounds__(512) __attribute__((amdgpu_waves_per_eu(2, 2)))
void spatial_kernel(const float* __restrict__ data,
                    const int* __restrict__ roffSg, const int2* __restrict__ edgeSg,
                    const float* __restrict__ c1w, const float* __restrict__ c1b,
                    const float* __restrict__ w1T, const float* __restrict__ f1b,
                    float* __restrict__ outS)
{
  __shared__ __align__(16) float featsS[NSc][20];
  __shared__ float spkF[NSc][64];
  __shared__ int roffS[NSc + 1];
  __shared__ int2 edgeS[ESc];

  const int tid = threadIdx.x;
  const int lane = tid & 63;
  const int wv = tid >> 6;
  const int b = blockIdx.x;

  if (tid < NSc + 1) roffS[tid] = roffSg[tid];
  if (tid < ESc) edgeS[tid] = edgeSg[tid];

  float wc1[16];
#pragma unroll
  for (int r = 0; r < 16; ++r) wc1[r] = c1w[r * COc + lane];
  const float bcv1 = c1b[lane];

  // wave -> output group: waves 0-3 own 3 outputs, 4-7 own 2 (total 20)
  const int j0 = (wv < 4) ? wv * 3 : 12 + (wv - 4) * 2;
  const int jn = (wv < 4) ? 3 : 2;
  float wfcr[NSc * 3];
#pragma unroll
  for (int i = 0; i < NSc; ++i) {
#pragma unroll
    for (int jj = 0; jj < 3; ++jj)
      wfcr[i * 3 + jj] = (jj < jn) ? w1T[(j0 + jj) * (NSc * COc) + i * COc + lane] : 0.0f;
  }
  float bj[3];
#pragma unroll
  for (int jj = 0; jj < 3; ++jj) bj[jj] = (jj < jn) ? f1b[j0 + jj] : 0.0f;

  float cm[5] = {0, 0, 0, 0, 0};
  float hm[3] = {0, 0, 0}, hsum[3] = {0, 0, 0};

  const float* dbase = data + (size_t)b * (2 * NSc * 2 * Tc);
  __syncthreads();

#pragma unroll 1
  for (int t = 0; t < Tc; ++t) {
    // hops: wave c handles channel c, lane = node, all in-wave (no barrier between k)
    if (wv < 4) {
      const int c = wv;
      if (lane < NSc) {
        featsS[lane][c] = dbase[((lane + (c >> 1) * NSc) * 2 + (c & 1)) * Tc + t];
#pragma unroll
        for (int k = 1; k <= 3; ++k) {
          float v = 0.0f;
          int e0 = roffS[lane], e1 = roffS[lane + 1];
          for (int e = e0; e < e1; ++e) {
            int2 ed = edgeS[e];
            v = fmaf(__int_as_float(ed.y), featsS[ed.x][(k - 1) * 4 + c], v);
          }
          featsS[lane][k * 4 + c] = v;
        }
      }
    }
    __syncthreads();
    // conv + LIF; spike as float into spkF
#pragma unroll
    for (int q = 0; q < 5; ++q) {
      int i = wv + 8 * q;
      if (i < NSc) {
        const float4* f4 = (const float4*)featsS[i];
        float4 f0 = f4[0], f1 = f4[1], f2 = f4[2], f3 = f4[3];
        float acc = bcv1;
        acc = fmaf(f0.x, wc1[0], acc);  acc = fmaf(f0.y, wc1[1], acc);
        acc = fmaf(f0.z, wc1[2], acc);  acc = fmaf(f0.w, wc1[3], acc);
        acc = fmaf(f1.x, wc1[4], acc);  acc = fmaf(f1.y, wc1[5], acc);
        acc = fmaf(f1.z, wc1[6], acc);  acc = fmaf(f1.w, wc1[7], acc);
        acc = fmaf(f2.x, wc1[8], acc);  acc = fmaf(f2.y, wc1[9], acc);
        acc = fmaf(f2.z, wc1[10], acc); acc = fmaf(f2.w, wc1[11], acc);
        acc = fmaf(f3.x, wc1[12], acc); acc = fmaf(f3.y, wc1[13], acc);
        acc = fmaf(f3.z, wc1[14], acc); acc = fmaf(f3.w, wc1[15], acc);
        float old = cm[q];
        float m = (old * 0.2f) * ((old > 0.5f) ? 0.0f : 1.0f) + acc;
        cm[q] = m;
        spkF[i][lane] = (m > 0.5f) ? 1.0f : 0.0f;
      }
    }
    __syncthreads();
    // fc: register weights, float spike gates
    float p0 = 0.0f, p1 = 0.0f, p2 = 0.0f;
#pragma unroll
    for (int i = 0; i < NSc; ++i) {
      float g = spkF[i][lane];
      p0 = fmaf(g, wfcr[i * 3 + 0], p0);
      p1 = fmaf(g, wfcr[i * 3 + 1], p1);
      p2 = fmaf(g, wfcr[i * 3 + 2], p2);
    }
#pragma unroll
    for (int off = 32; off >= 1; off >>= 1) {
      p0 += __shfl_xor(p0, off, 64);
      p1 += __shfl_xor(p1, off, 64);
      p2 += __shfl_xor(p2, off, 64);
    }
    float av[3] = {p0, p1, p2};
#pragma unroll
    for (int jj = 0; jj < 3; ++jj) {
      float m = hm[jj];
      m = (m * 0.2f) * ((m > 0.5f) ? 0.0f : 1.0f) + av[jj] + bj[jj];
      hm[jj] = m;
      hsum[jj] += (m > 0.5f) ? 1.0f : 0.0f;
    }
  }
  if (lane == 0) {
    for (int jj = 0; jj < jn; ++jj)
      outS[b * NCc + j0 + jj] = hsum[jj] / (float)Tc;
  }
}

// ---------------- temporal: phase1 conv chain records spike bits; phase2 single weight pass ----------------
__global__ __launch_bounds__(512) __attribute__((amdgpu_waves_per_eu(2, 2)))
void temporal_kernel(const float* __restrict__ data,
                     const int* __restrict__ roffTg, const int2* __restrict__ edgeTg,
                     const float* __restrict__ c2w, const float* __restrict__ c2b,
                     const float* __restrict__ wT, const float* __restrict__ tf1b,
                     float* __restrict__ outT)
{
  __shared__ __align__(16) float featsT[Tc][20];  // 26000 B
  __shared__ int roffT[Tc + 1];
  __shared__ int2 edgeT[ETc];
  __shared__ u32 spkLo[Tc * 64];                  // 83200 B
  __shared__ u8  spkHi[Tc * 64];                  // 20800 B

  const int tid = threadIdx.x;
  const int lane = tid & 63;
  const int wv = tid >> 6;
  const int b = blockIdx.x;

  for (int i = tid; i < Tc + 1; i += 512) roffT[i] = roffTg[i];
  for (int i = tid; i < ETc; i += 512) edgeT[i] = edgeTg[i];

  float wc2[16];
#pragma unroll
  for (int r = 0; r < 16; ++r) wc2[r] = c2w[r * COc + lane];
  const float bcv2 = c2b[lane];

  float tm[41];
  u64 spk[41];
#pragma unroll
  for (int q = 0; q < 41; ++q) { tm[q] = 0.0f; spk[q] = 0ull; }

  const float* dbase = data + (size_t)b * (2 * NSc * 2 * Tc);
  __syncthreads();

  // ---- phase 1: conv chain over 39 steps, accumulate spike bits in registers ----
#pragma unroll 1
  for (int s = 0; s < NSc; ++s) {
#pragma unroll
    for (int k2 = 0; k2 < 3; ++k2) {
      int idx = tid + 512 * k2;
      if (idx < Tc * 4) {
        int c = idx / Tc, t = idx - c * Tc;
        featsT[t][c] = dbase[((s + (c >> 1) * NSc) * 2 + (c & 1)) * Tc + t];
      }
    }
    __syncthreads();
#pragma unroll
    for (int k = 1; k <= 3; ++k) {
#pragma unroll
      for (int k2 = 0; k2 < 3; ++k2) {
        int idx = tid + 512 * k2;
        if (idx < Tc * 4) {
          int t = idx >> 2, c = idx & 3;
          float v = 0.0f;
          int e0 = roffT[t], e1 = roffT[t + 1];
          for (int e = e0; e < e1; ++e) {
            int2 ed = edgeT[e];
            v = fmaf(__int_as_float(ed.y), featsT[ed.x][(k - 1) * 4 + c], v);
          }
          featsT[t][k * 4 + c] = v;
        }
      }
      __syncthreads();
    }
#pragma unroll
    for (int q = 0; q < 41; ++q) {
      int i = wv + 8 * q;
      if (i < Tc) {
        const float4* f4 = (const float4*)featsT[i];
        float4 f0 = f4[0], f1 = f4[1], f2 = f4[2], f3 = f4[3];
        float acc = bcv2;
        acc = fmaf(f0.x, wc2[0], acc);  acc = fmaf(f0.y, wc2[1], acc);
        acc = fmaf(f0.z, wc2[2], acc);  acc = fmaf(f0.w, wc2[3], acc);
        acc = fmaf(f1.x, wc2[4], acc);  acc = fmaf(f1.y, wc2[5], acc);
        acc = fmaf(f1.z, wc2[6], acc);  acc = fmaf(f1.w, wc2[7], acc);
        acc = fmaf(f2.x, wc2[8], acc);  acc = fmaf(f2.y, wc2[9], acc);
        acc = fmaf(f2.z, wc2[10], acc); acc = fmaf(f2.w, wc2[11], acc);
        acc = fmaf(f3.x, wc2[12], acc); acc = fmaf(f3.y, wc2[13], acc);
        acc = fmaf(f3.z, wc2[14], acc); acc = fmaf(f3.w, wc2[15], acc);
        float old = tm[q];
        float m = (old * 0.2f) * ((old > 0.5f) ? 0.0f : 1.0f) + acc;
        tm[q] = m;
        spk[q] |= (m > 0.5f) ? (1ull << s) : 0ull;
      }
    }
    __syncthreads();  // featsT reused next step
  }

  // dump spike bits to LDS (packed 32+7)
#pragma unroll
  for (int q = 0; q < 41; ++q) {
    int i = wv + 8 * q;
    if (i < Tc) {
      spkLo[i * 64 + lane] = (u32)spk[q];
      spkHi[i * 64 + lane] = (u8)(spk[q] >> 32);
    }
  }
  __syncthreads();

  // ---- phase 2: single pass over tfc1_w, accumulate per-step partials ----
  const int j0 = (wv < 4) ? wv * 3 : 12 + (wv - 4) * 2;
  const int jn = (wv < 4) ? 3 : 2;
  const float* pw0 = wT + (size_t)(j0 + 0) * (Tc * COc) + lane;
  const float* pw1 = wT + (size_t)(j0 + 1) * (Tc * COc) + lane;
  const float* pw2 = wT + (size_t)((jn > 2) ? j0 + 2 : j0) * (Tc * COc) + lane;

  float ya0[NSc], ya1[NSc], ya2[NSc];
#pragma unroll
  for (int s = 0; s < NSc; ++s) { ya0[s] = 0.0f; ya1[s] = 0.0f; ya2[s] = 0.0f; }

  float w0 = pw0[0], w1 = pw1[0], w2 = pw2[0];
#pragma unroll 1
  for (int i = 0; i < Tc; ++i) {
    u32 lo = spkLo[i * 64 + lane];
    u32 hi = (u32)spkHi[i * 64 + lane];
    int ip = (i + 1 < Tc) ? (i + 1) : (Tc - 1);
    float nw0 = pw0[ip * COc], nw1 = pw1[ip * COc], nw2 = pw2[ip * COc];
#pragma unroll
    for (int s = 0; s < 32; ++s) {
      float g = (float)((lo >> s) & 1u);
      ya0[s] = fmaf(g, w0, ya0[s]);
      ya1[s] = fmaf(g, w1, ya1[s]);
      ya2[s] = fmaf(g, w2, ya2[s]);
    }
#pragma unroll
    for (int s = 0; s < 7; ++s) {
      float g = (float)((hi >> s) & 1u);
      ya0[32 + s] = fmaf(g, w0, ya0[32 + s]);
      ya1[32 + s] = fmaf(g, w1, ya1[32 + s]);
      ya2[32 + s] = fmaf(g, w2, ya2[32 + s]);
    }
    w0 = nw0; w1 = nw1; w2 = nw2;
  }

  // cross-lane reduce all per-step partials
#pragma unroll
  for (int s = 0; s < NSc; ++s) {
#pragma unroll
    for (int off = 32; off >= 1; off >>= 1) {
      ya0[s] += __shfl_xor(ya0[s], off, 64);
      ya1[s] += __shfl_xor(ya1[s], off, 64);
      ya2[s] += __shfl_xor(ya2[s], off, 64);
    }
  }

  // h-LIF recurrence over steps
  float bj0 = tf1b[j0];
  float bj1 = tf1b[j0 + 1];
  float bj2 = (jn > 2) ? tf1b[j0 + 2] : 0.0f;
  float m0 = 0.0f, m1 = 0.0f, m2 = 0.0f;
  float h0 = 0.0f, h1 = 0.0f, h2 = 0.0f;
#pragma unroll
  for (int s = 0; s < NSc; ++s) {
    m0 = (m0 * 0.2f) * ((m0 > 0.5f) ? 0.0f : 1.0f) + ya0[s] + bj0;
    m1 = (m1 * 0.2f) * ((m1 > 0.5f) ? 0.0f : 1.0f) + ya1[s] + bj1;
    m2 = (m2 * 0.2f) * ((m2 > 0.5f) ? 0.0f : 1.0f) + ya2[s] + bj2;
    h0 += (m0 > 0.5f) ? 1.0f : 0.0f;
    h1 += (m1 > 0.5f) ? 1.0f : 0.0f;
    h2 += (m2 > 0.5f) ? 1.0f : 0.0f;
  }
  if (lane == 0) {
    outT[b * NCc + j0] = h0 / (float)NSc;
    outT[b * NCc + j0 + 1] = h1 / (float)NSc;
    if (jn > 2) outT[b * NCc + j0 + 2] = h2 / (float)NSc;
  }
}

__global__ void combine_kernel(const float* __restrict__ a, const float* __restrict__ c,
                               float* __restrict__ o) {
  int i = blockIdx.x * 256 + threadIdx.x;
  if (i < Bc * NCc) o[i] = (a[i] + c[i]) * 0.5f;
}

extern "C" void kernel_launch(void* const* d_in, const int* in_sizes, int n_in,
                              void* d_out, int out_size, void* d_ws, size_t ws_size,
                              hipStream_t stream) {
  const float* data = (const float*)d_in[0];
  const int*   eiS  = (const int*)d_in[1];
  const int*   eiT  = (const int*)d_in[2];
  const float* c1w  = (const float*)d_in[3];
  const float* c1b  = (const float*)d_in[4];
  const float* c2w  = (const float*)d_in[5];
  const float* c2b  = (const float*)d_in[6];
  const float* f1w  = (const float*)d_in[7];
  const float* f1b  = (const float*)d_in[8];
  const float* tf1w = (const float*)d_in[9];
  const float* tf1b = (const float*)d_in[10];
  float* out = (float*)d_out;
  int* wsI = (int*)d_ws;
  float* wsF = (float*)d_ws;

  prep_graph<<<2, 256, 0, stream>>>(eiS, eiT, wsI, wsF);
  prep_w<<<(NCc * Tc * COc + 255) / 256, 256, 0, stream>>>(tf1w, wsF + WS_WT,
                                                           f1w, wsF + WS_W1T);
  spatial_kernel<<<Bc, 512, 0, stream>>>(data,
                                         wsI + WS_ROFF_S, (const int2*)(wsI + WS_EDGE_S),
                                         c1w, c1b, wsF + WS_W1T, f1b, wsF + WS_OUTS);
  temporal_kernel<<<Bc, 512, 0, stream>>>(data,
                                          wsI + WS_ROFF_T, (const int2*)(wsI + WS_EDGE_T),
                                          c2w, c2b, wsF + WS_WT, tf1b, wsF + WS_OUTT);
  combine_kernel<<<(Bc * NCc + 255) / 256, 256, 0, stream>>>(wsF + WS_OUTS,
                                                             wsF + WS_OUTT, out);
}

// Round 5
// 2840.225 us; speedup vs baseline: 2.4290x; 2.4290x over previous
//
#include <hip/hip_runtime.h>

typedef unsigned int u32;
typedef unsigned long long u64;

#define Bc 256
#define Tc 325
#define NSc 39
#define COc 64
#define NCc 20
#define ESc 117
#define ETc 648

// workspace layout in 4-byte units
#define WS_ROFF_S 0        // 40 ints
#define WS_EDGE_S 64       // 117 int2 (234 w)
#define WS_DINV_S 304      // 39 f
#define WS_ROFF_T 352      // 326 ints
#define WS_EDGE_T 680      // 648 int2 (1296 w)
#define WS_DINV_T 1976     // 325 f
#define WS_W1T    2304     // 49920 f  (fc1_w transposed [20][2496])
#define WS_W2T    52224    // 416000 f (tfc1_w transposed [20][20800])

// ---------------- prep: CSR (by dst, interleaved {src, nrm}) ----------------
__global__ void prep_graph(const int* __restrict__ eiS, const int* __restrict__ eiT,
                           int* __restrict__ wsI, float* __restrict__ wsF) {
  const int which = blockIdx.x;
  const int* ei = which ? eiT : eiS;
  const int nE = which ? ETc : ESc;
  const int nN = which ? Tc : NSc;
  int* roff = wsI + (which ? WS_ROFF_T : WS_ROFF_S);
  int2* edge = (int2*)(wsI + (which ? WS_EDGE_T : WS_EDGE_S));
  float* dinv = wsF + (which ? WS_DINV_T : WS_DINV_S);
  const int* src = ei;
  const int* dst = ei + nE;
  for (int n = threadIdx.x; n < nN; n += blockDim.x) {
    int deg = 0, before = 0;
    for (int e = 0; e < nE; ++e) { deg += (dst[e] == n); before += (dst[e] < n); }
    roff[n] = before;
    if (n == nN - 1) roff[nN] = before + deg;
    dinv[n] = (deg > 0) ? (1.0f / sqrtf((float)deg)) : 0.0f;
  }
  __syncthreads();
  for (int n = threadIdx.x; n < nN; n += blockDim.x) {
    int cur = roff[n];
    float dn = dinv[n];
    for (int e = 0; e < nE; ++e) {
      if (dst[e] == n) {
        edge[cur] = make_int2(src[e], __float_as_int(dinv[src[e]] * dn));
        ++cur;
      }
    }
  }
}

// ---------------- prep: transpose both fc weights ----------------
__global__ void prep_w(const float* __restrict__ w1, float* __restrict__ w1T,
                       const float* __restrict__ w2, float* __restrict__ w2T) {
  int i = blockIdx.x * 256 + threadIdx.x;
  if (i < NCc * Tc * COc) {
    int j = i / (Tc * COc);
    int p = i - j * (Tc * COc);
    w2T[i] = w2[p * NCc + j];
  }
  if (i < NCc * NSc * COc) {
    int j = i / (NSc * COc);
    int p = i - j * (NSc * COc);
    w1T[i] = w1[p * NCc + j];
  }
}

// ---------------- fused 4-phase kernel: 1 batch per block ----------------
__global__ __launch_bounds__(1024, 4)
void lif_fused(const float* __restrict__ data,
               const int* __restrict__ roffSg, const int2* __restrict__ edgeSg,
               const int* __restrict__ roffTg, const int2* __restrict__ edgeTg,
               const float* __restrict__ c1w, const float* __restrict__ c1b,
               const float* __restrict__ c2w, const float* __restrict__ c2b,
               const float* __restrict__ w1T, const float* __restrict__ f1b,
               const float* __restrict__ w2T, const float* __restrict__ tf1b,
               float* __restrict__ out)
{
  __shared__ u32 spk32[26000];                 // 104000 B: u64 spike words (padded)
  __shared__ __align__(16) float feats[6500];  // 26000 B: P1 [39][16][8] / P3 [325][20]
  __shared__ float partials[4][4][8][5];       // 2560 B
  __shared__ float outS_l[NCc];
  __shared__ int roffS[NSc + 1];
  __shared__ int2 edgeS[ESc];
  __shared__ int roffT[Tc + 1];
  __shared__ int2 edgeT[ETc];

  const int tid = threadIdx.x;
  const int lane = tid & 63;
  const int wv = tid >> 6;
  const int b = blockIdx.x;
  const int lhalf = lane >> 5;
  const int lbit = lane & 31;
  const float* dbase = data + (size_t)b * (2 * NSc * 2 * Tc);

  for (int i = tid; i < NSc + 1; i += 1024) roffS[i] = roffSg[i];
  for (int i = tid; i < ESc; i += 1024) edgeS[i] = edgeSg[i];
  for (int i = tid; i < Tc + 1; i += 1024) roffT[i] = roffTg[i];
  for (int i = tid; i < ETc; i += 1024) edgeT[i] = edgeTg[i];
  __syncthreads();

  // ============ P1: spatial conv chain -> spike words spk[t][i] ============
  {
    float wc[16];
#pragma unroll
    for (int r = 0; r < 16; ++r) wc[r] = c1w[r * COc + lane];
    const float bcv = c1b[lane];
    float cm[3] = {0.0f, 0.0f, 0.0f};
    const int nq = (wv < 7) ? 3 : 2;

#pragma unroll 1
    for (int tb = 0; tb < 41; ++tb) {
      const int t0 = tb * 8;
      // stage x for 8 t's: feats[n][c][dt], layout n*128 + c*8 + dt
#pragma unroll
      for (int it = 0; it < 2; ++it) {
        int idx = tid + it * 1024;
        if (idx < NSc * 32) {
          int n = idx >> 5, c = (idx >> 3) & 3, dt = idx & 7;
          int t = t0 + dt;
          float v = (t < Tc) ? dbase[(n + (c >> 1) * NSc) * 650 + (c & 1) * 325 + t] : 0.0f;
          feats[n * 128 + c * 8 + dt] = v;
        }
      }
      __syncthreads();
      // 3 hops
#pragma unroll
      for (int k = 1; k <= 3; ++k) {
#pragma unroll
        for (int it = 0; it < 2; ++it) {
          int idx = tid + it * 1024;
          if (idx < NSc * 32) {
            int n = idx >> 5, c = (idx >> 3) & 3, dt = idx & 7;
            float v = 0.0f;
            for (int e = roffS[n]; e < roffS[n + 1]; ++e) {
              int2 ed = edgeS[e];
              v = fmaf(__int_as_float(ed.y), feats[ed.x * 128 + ((k - 1) * 4 + c) * 8 + dt], v);
            }
            feats[n * 128 + (k * 4 + c) * 8 + dt] = v;
          }
        }
        __syncthreads();
      }
      // conv + LIF + ballot -> LDS spike words
#pragma unroll
      for (int q = 0; q < 3; ++q) {
        if (q < nq) {
          int i = wv + 16 * q;
          float za[8];
#pragma unroll
          for (int dt = 0; dt < 8; ++dt) za[dt] = bcv;
#pragma unroll
          for (int r = 0; r < 16; ++r) {
            float4 fa = *(const float4*)&feats[i * 128 + r * 8];
            float4 fb = *(const float4*)&feats[i * 128 + r * 8 + 4];
            za[0] = fmaf(fa.x, wc[r], za[0]);
            za[1] = fmaf(fa.y, wc[r], za[1]);
            za[2] = fmaf(fa.z, wc[r], za[2]);
            za[3] = fmaf(fa.w, wc[r], za[3]);
            za[4] = fmaf(fb.x, wc[r], za[4]);
            za[5] = fmaf(fb.y, wc[r], za[5]);
            za[6] = fmaf(fb.z, wc[r], za[6]);
            za[7] = fmaf(fb.w, wc[r], za[7]);
          }
#pragma unroll
          for (int dt = 0; dt < 8; ++dt) {
            if (t0 + dt < Tc) {
              float old = cm[q];
              float m = (old * 0.2f) * ((old > 0.5f) ? 0.0f : 1.0f) + za[dt];
              cm[q] = m;
              u64 wd = __ballot(m > 0.5f);
              if (lane == 0) *(u64*)&spk32[((t0 + dt) * NSc + i) * 2] = wd;
            }
          }
        }
      }
      __syncthreads();
    }
  }

  // ============ P2: spatial fc (binary GEMM) + h-LIF ============
  {
    const int jg = wv >> 2, iq = wv & 3;
    const int j0 = jg * 5;
    const float bj1 = f1b[wv];
    const float bj2 = (wv < 4) ? f1b[16 + wv] : 0.0f;
    float hm0 = 0.0f, hs0 = 0.0f, hm1 = 0.0f, hs1 = 0.0f;

#pragma unroll 1
    for (int ch = 0; ch < 41; ++ch) {
      const int s0 = ch * 8;
      float ya[8][5];
#pragma unroll
      for (int ds = 0; ds < 8; ++ds)
#pragma unroll
        for (int jj = 0; jj < 5; ++jj) ya[ds][jj] = 0.0f;

#pragma unroll 1
      for (int ii = 0; ii < 10; ++ii) {
        int i = iq * 10 + ii;
        if (i < NSc) {
          const float* wp = w1T + i * COc + lane;
          float w0 = wp[(j0 + 0) * (NSc * COc)];
          float w1 = wp[(j0 + 1) * (NSc * COc)];
          float w2 = wp[(j0 + 2) * (NSc * COc)];
          float w3 = wp[(j0 + 3) * (NSc * COc)];
          float w4 = wp[(j0 + 4) * (NSc * COc)];
          int base = (s0 * NSc + i) * 2 + lhalf;
#pragma unroll
          for (int ds = 0; ds < 8; ++ds) {
            u32 wb = spk32[base + ds * (NSc * 2)];
            float g = (float)((wb >> lbit) & 1u);
            ya[ds][0] = fmaf(g, w0, ya[ds][0]);
            ya[ds][1] = fmaf(g, w1, ya[ds][1]);
            ya[ds][2] = fmaf(g, w2, ya[ds][2]);
            ya[ds][3] = fmaf(g, w3, ya[ds][3]);
            ya[ds][4] = fmaf(g, w4, ya[ds][4]);
          }
        }
      }
      // full butterfly over 64 lanes
#pragma unroll
      for (int off = 32; off >= 1; off >>= 1)
#pragma unroll
        for (int ds = 0; ds < 8; ++ds)
#pragma unroll
          for (int jj = 0; jj < 5; ++jj)
            ya[ds][jj] += __shfl_xor(ya[ds][jj], off, 64);
      if (lane == 0) {
#pragma unroll
        for (int ds = 0; ds < 8; ++ds)
#pragma unroll
          for (int jj = 0; jj < 5; ++jj)
            partials[jg][iq][ds][jj] = ya[ds][jj];
      }
      __syncthreads();
      // reduce + LIF: wave wv -> j=wv (and 16+wv for wv<4)
      {
        const int rjg = wv / 5, rjj = wv % 5;
#pragma unroll
        for (int ds = 0; ds < 8; ++ds) {
          int s = s0 + ds;
          if (s < Tc) {
            float y = partials[rjg][0][ds][rjj] + partials[rjg][1][ds][rjj]
                    + partials[rjg][2][ds][rjj] + partials[rjg][3][ds][rjj] + bj1;
            float m = hm0;
            m = (m * 0.2f) * ((m > 0.5f) ? 0.0f : 1.0f) + y;
            hm0 = m;
            hs0 += (m > 0.5f) ? 1.0f : 0.0f;
          }
        }
        if (wv < 4) {
          const int j2 = 16 + wv, g2 = j2 / 5, jj2 = j2 % 5;
#pragma unroll
          for (int ds = 0; ds < 8; ++ds) {
            int s = s0 + ds;
            if (s < Tc) {
              float y = partials[g2][0][ds][jj2] + partials[g2][1][ds][jj2]
                      + partials[g2][2][ds][jj2] + partials[g2][3][ds][jj2] + bj2;
              float m = hm1;
              m = (m * 0.2f) * ((m > 0.5f) ? 0.0f : 1.0f) + y;
              hm1 = m;
              hs1 += (m > 0.5f) ? 1.0f : 0.0f;
            }
          }
        }
      }
      __syncthreads();
    }
    if (lane == 0) {
      outS_l[wv] = hs0 / (float)Tc;
      if (wv < 4) outS_l[16 + wv] = hs1 / (float)Tc;
    }
  }
  __syncthreads();

  // ============ P3: temporal conv chain -> spike words spk[s][i] ============
  {
    float wc[16];
#pragma unroll
    for (int r = 0; r < 16; ++r) wc[r] = c2w[r * COc + lane];
    const float bcv = c2b[lane];
    float tm[21];
#pragma unroll
    for (int q = 0; q < 21; ++q) tm[q] = 0.0f;
    const int nq = (wv < 5) ? 21 : 20;

#pragma unroll 1
    for (int s = 0; s < NSc; ++s) {
      // stage x_s: feats[t][c], layout t*20 + c
#pragma unroll
      for (int it = 0; it < 2; ++it) {
        int idx = tid + it * 1024;
        if (idx < Tc * 4) {
          int c = idx / Tc, t = idx - c * Tc;
          feats[t * 20 + c] = dbase[(s + (c >> 1) * NSc) * 650 + (c & 1) * 325 + t];
        }
      }
      __syncthreads();
#pragma unroll
      for (int k = 1; k <= 3; ++k) {
#pragma unroll
        for (int it = 0; it < 2; ++it) {
          int idx = tid + it * 1024;
          if (idx < Tc * 4) {
            int t = idx >> 2, c = idx & 3;
            float v = 0.0f;
            for (int e = roffT[t]; e < roffT[t + 1]; ++e) {
              int2 ed = edgeT[e];
              v = fmaf(__int_as_float(ed.y), feats[ed.x * 20 + (k - 1) * 4 + c], v);
            }
            feats[t * 20 + k * 4 + c] = v;
          }
        }
        __syncthreads();
      }
#pragma unroll
      for (int q = 0; q < 21; ++q) {
        if (q < nq) {
          int i = wv + 16 * q;
          float4 f0 = *(const float4*)&feats[i * 20 + 0];
          float4 f1 = *(const float4*)&feats[i * 20 + 4];
          float4 f2 = *(const float4*)&feats[i * 20 + 8];
          float4 f3 = *(const float4*)&feats[i * 20 + 12];
          float acc = bcv;
          acc = fmaf(f0.x, wc[0], acc);  acc = fmaf(f0.y, wc[1], acc);
          acc = fmaf(f0.z, wc[2], acc);  acc = fmaf(f0.w, wc[3], acc);
          acc = fmaf(f1.x, wc[4], acc);  acc = fmaf(f1.y, wc[5], acc);
          acc = fmaf(f1.z, wc[6], acc);  acc = fmaf(f1.w, wc[7], acc);
          acc = fmaf(f2.x, wc[8], acc);  acc = fmaf(f2.y, wc[9], acc);
          acc = fmaf(f2.z, wc[10], acc); acc = fmaf(f2.w, wc[11], acc);
          acc = fmaf(f3.x, wc[12], acc); acc = fmaf(f3.y, wc[13], acc);
          acc = fmaf(f3.z, wc[14], acc); acc = fmaf(f3.w, wc[15], acc);
          float old = tm[q];
          float m = (old * 0.2f) * ((old > 0.5f) ? 0.0f : 1.0f) + acc;
          tm[q] = m;
          u64 wd = __ballot(m > 0.5f);
          if (lane == 0) *(u64*)&spk32[(s * Tc + i) * 2] = wd;
        }
      }
      __syncthreads();
    }
  }

  // ============ P4: temporal fc (binary GEMM) + h-LIF + final combine ============
  {
    const int jg = wv >> 2, iq = wv & 3;
    const int j0 = jg * 5;
    const int i0 = iq * 82;
    const int i1 = (i0 + 82 < Tc) ? i0 + 82 : Tc;
    const float bj1 = tf1b[wv];
    const float bj2 = (wv < 4) ? tf1b[16 + wv] : 0.0f;
    float hm0 = 0.0f, hs0 = 0.0f, hm1 = 0.0f, hs1 = 0.0f;

#pragma unroll 1
    for (int ch = 0; ch < 5; ++ch) {
      const int s0 = ch * 8;
      float ya[8][5];
#pragma unroll
      for (int ds = 0; ds < 8; ++ds)
#pragma unroll
        for (int jj = 0; jj < 5; ++jj) ya[ds][jj] = 0.0f;

#pragma unroll 1
      for (int i = i0; i < i1; ++i) {
        const float* wp = w2T + i * COc + lane;
        float w0 = wp[(j0 + 0) * (Tc * COc)];
        float w1 = wp[(j0 + 1) * (Tc * COc)];
        float w2 = wp[(j0 + 2) * (Tc * COc)];
        float w3 = wp[(j0 + 3) * (Tc * COc)];
        float w4 = wp[(j0 + 4) * (Tc * COc)];
        int base = (s0 * Tc + i) * 2 + lhalf;
#pragma unroll
        for (int ds = 0; ds < 8; ++ds) {
          u32 wb = spk32[base + ds * (Tc * 2)];
          float g = (float)((wb >> lbit) & 1u);
          ya[ds][0] = fmaf(g, w0, ya[ds][0]);
          ya[ds][1] = fmaf(g, w1, ya[ds][1]);
          ya[ds][2] = fmaf(g, w2, ya[ds][2]);
          ya[ds][3] = fmaf(g, w3, ya[ds][3]);
          ya[ds][4] = fmaf(g, w4, ya[ds][4]);
        }
      }
#pragma unroll
      for (int off = 32; off >= 1; off >>= 1)
#pragma unroll
        for (int ds = 0; ds < 8; ++ds)
#pragma unroll
          for (int jj = 0; jj < 5; ++jj)
            ya[ds][jj] += __shfl_xor(ya[ds][jj], off, 64);
      if (lane == 0) {
#pragma unroll
        for (int ds = 0; ds < 8; ++ds)
#pragma unroll
          for (int jj = 0; jj < 5; ++jj)
            partials[jg][iq][ds][jj] = ya[ds][jj];
      }
      __syncthreads();
      {
        const int rjg = wv / 5, rjj = wv % 5;
#pragma unroll
        for (int ds = 0; ds < 8; ++ds) {
          int s = s0 + ds;
          if (s < NSc) {
            float y = partials[rjg][0][ds][rjj] + partials[rjg][1][ds][rjj]
                    + partials[rjg][2][ds][rjj] + partials[rjg][3][ds][rjj] + bj1;
            float m = hm0;
            m = (m * 0.2f) * ((m > 0.5f) ? 0.0f : 1.0f) + y;
            hm0 = m;
            hs0 += (m > 0.5f) ? 1.0f : 0.0f;
          }
        }
        if (wv < 4) {
          const int j2 = 16 + wv, g2 = j2 / 5, jj2 = j2 % 5;
#pragma unroll
          for (int ds = 0; ds < 8; ++ds) {
            int s = s0 + ds;
            if (s < NSc) {
              float y = partials[g2][0][ds][jj2] + partials[g2][1][ds][jj2]
                      + partials[g2][2][ds][jj2] + partials[g2][3][ds][jj2] + bj2;
              float m = hm1;
              m = (m * 0.2f) * ((m > 0.5f) ? 0.0f : 1.0f) + y;
              hm1 = m;
              hs1 += (m > 0.5f) ? 1.0f : 0.0f;
            }
          }
        }
      }
      __syncthreads();
    }
    if (lane == 0) {
      out[b * NCc + wv] = (outS_l[wv] + hs0 / (float)NSc) * 0.5f;
      if (wv < 4)
        out[b * NCc + 16 + wv] = (outS_l[16 + wv] + hs1 / (float)NSc) * 0.5f;
    }
  }
}

extern "C" void kernel_launch(void* const* d_in, const int* in_sizes, int n_in,
                              void* d_out, int out_size, void* d_ws, size_t ws_size,
                              hipStream_t stream) {
  const float* data = (const float*)d_in[0];
  const int*   eiS  = (const int*)d_in[1];
  const int*   eiT  = (const int*)d_in[2];
  const float* c1w  = (const float*)d_in[3];
  const float* c1b  = (const float*)d_in[4];
  const float* c2w  = (const float*)d_in[5];
  const float* c2b  = (const float*)d_in[6];
  const float* f1w  = (const float*)d_in[7];
  const float* f1b  = (const float*)d_in[8];
  const float* tf1w = (const float*)d_in[9];
  const float* tf1b = (const float*)d_in[10];
  float* out = (float*)d_out;
  int* wsI = (int*)d_ws;
  float* wsF = (float*)d_ws;

  prep_graph<<<2, 256, 0, stream>>>(eiS, eiT, wsI, wsF);
  prep_w<<<(NCc * Tc * COc + 255) / 256, 256, 0, stream>>>(f1w, wsF + WS_W1T,
                                                           tf1w, wsF + WS_W2T);
  lif_fused<<<Bc, 1024, 0, stream>>>(data,
                                     wsI + WS_ROFF_S, (const int2*)(wsI + WS_EDGE_S),
                                     wsI + WS_ROFF_T, (const int2*)(wsI + WS_EDGE_T),
                                     c1w, c1b, c2w, c2b,
                                     wsF + WS_W1T, f1b, wsF + WS_W2T, tf1b,
                                     out);
}

// Round 6
// 2547.119 us; speedup vs baseline: 2.7085x; 1.1151x over previous
//
#include <hip/hip_runtime.h>

typedef unsigned int u32;
typedef unsigned long long u64;

#define Bc 256
#define Tc 325
#define NSc 39
#define COc 64
#define NCc 20
#define ESc 117
#define ETc 648

// workspace layout in 4-byte units
#define WS_ROFF_S 0        // 40 ints
#define WS_EDGE_S 64       // 117 int2 (234 w)
#define WS_DINV_S 304      // 39 f
#define WS_ROFF_T 352      // 326 ints
#define WS_EDGE_T 680      // 648 int2 (1296 w)
#define WS_DINV_T 1976     // 325 f
#define WS_W1T    2304     // 49920 f  (fc1_w transposed [20][2496])
#define WS_W2T    52224    // 416000 f (tfc1_w transposed [20][20800])

// ---------------- prep: CSR (by dst, interleaved {src, nrm}) ----------------
__global__ void prep_graph(const int* __restrict__ eiS, const int* __restrict__ eiT,
                           int* __restrict__ wsI, float* __restrict__ wsF) {
  const int which = blockIdx.x;
  const int* ei = which ? eiT : eiS;
  const int nE = which ? ETc : ESc;
  const int nN = which ? Tc : NSc;
  int* roff = wsI + (which ? WS_ROFF_T : WS_ROFF_S);
  int2* edge = (int2*)(wsI + (which ? WS_EDGE_T : WS_EDGE_S));
  float* dinv = wsF + (which ? WS_DINV_T : WS_DINV_S);
  const int* src = ei;
  const int* dst = ei + nE;
  for (int n = threadIdx.x; n < nN; n += blockDim.x) {
    int deg = 0, before = 0;
    for (int e = 0; e < nE; ++e) { deg += (dst[e] == n); before += (dst[e] < n); }
    roff[n] = before;
    if (n == nN - 1) roff[nN] = before + deg;
    dinv[n] = (deg > 0) ? (1.0f / sqrtf((float)deg)) : 0.0f;
  }
  __syncthreads();
  for (int n = threadIdx.x; n < nN; n += blockDim.x) {
    int cur = roff[n];
    float dn = dinv[n];
    for (int e = 0; e < nE; ++e) {
      if (dst[e] == n) {
        edge[cur] = make_int2(src[e], __float_as_int(dinv[src[e]] * dn));
        ++cur;
      }
    }
  }
}

// ---------------- prep: transpose both fc weights ----------------
__global__ void prep_w(const float* __restrict__ w1, float* __restrict__ w1T,
                       const float* __restrict__ w2, float* __restrict__ w2T) {
  int i = blockIdx.x * 256 + threadIdx.x;
  if (i < NCc * Tc * COc) {
    int j = i / (Tc * COc);
    int p = i - j * (Tc * COc);
    w2T[i] = w2[p * NCc + j];
  }
  if (i < NCc * NSc * COc) {
    int j = i / (NSc * COc);
    int p = i - j * (NSc * COc);
    w1T[i] = w1[p * NCc + j];
  }
}

// ---------------- fused kernel: 1 batch per block ----------------
__global__ __launch_bounds__(1024, 4)
void lif_fused(const float* __restrict__ data,
               const int* __restrict__ roffSg, const int2* __restrict__ edgeSg,
               const int* __restrict__ roffTg, const int2* __restrict__ edgeTg,
               const float* __restrict__ c1w, const float* __restrict__ c1b,
               const float* __restrict__ c2w, const float* __restrict__ c2b,
               const float* __restrict__ w1T, const float* __restrict__ f1b,
               const float* __restrict__ w2T, const float* __restrict__ tf1b,
               float* __restrict__ out)
{
  __shared__ __align__(16) float feats[6500];   // A: [39][16][8] / B: [325][20]
  __shared__ u32 spkT[40 * Tc * 2];             // 104000 B (row 39 = pad)
  __shared__ u32 spkA[8 * 40 * 2];              // 2560 B (i=39 = pad, zeroed)
  __shared__ float partbuf[1280];               // A: [8][16][5]=640 / C: [5][3][20][4]=1200
  __shared__ float outS_l[NCc];
  __shared__ int roffS[NSc + 1];
  __shared__ int2 edgeS[ESc];
  __shared__ int roffT[Tc + 1];
  __shared__ int2 edgeT[ETc];

  const int tid = threadIdx.x;
  const int lane = tid & 63;
  const int wv = tid >> 6;
  const int b = blockIdx.x;
  const int lhalf = lane >> 5;
  const int lbit = lane & 31;
  const float* dbase = data + (size_t)b * (2 * NSc * 2 * Tc);

  for (int i = tid; i < NSc + 1; i += 1024) roffS[i] = roffSg[i];
  for (int i = tid; i < ESc; i += 1024) edgeS[i] = edgeSg[i];
  for (int i = tid; i < Tc + 1; i += 1024) roffT[i] = roffTg[i];
  for (int i = tid; i < ETc; i += 1024) edgeT[i] = edgeTg[i];
  if (tid < 640) spkA[tid] = 0u;
  __syncthreads();

  // ============ Phase A: spatial conv + fc, fused per 8-t tile ============
  {
    float wc[16];
#pragma unroll
    for (int r = 0; r < 16; ++r) wc[r] = c1w[r * COc + lane];
    const float bcv = c1b[lane];
    float cm[3] = {0.0f, 0.0f, 0.0f};
    const int nq = (wv < 7) ? 3 : 2;

    // register-resident fc weights: wave = (jgA 4 groups of 5 j) x (iqA 4 quarters of 10 i)
    const int jgA = wv >> 2, iqA = wv & 3;
    float wfc[50];
#pragma unroll
    for (int ii = 0; ii < 10; ++ii) {
      int i = iqA * 10 + ii;
#pragma unroll
      for (int jj = 0; jj < 5; ++jj)
        wfc[ii * 5 + jj] = (i < NSc) ? w1T[(jgA * 5 + jj) * (NSc * COc) + i * COc + lane] : 0.0f;
    }
    const float bA0 = f1b[wv];
    const float bA1 = (wv < 4) ? f1b[16 + wv] : 0.0f;
    float hmA0 = 0.0f, hsA0 = 0.0f, hmA1 = 0.0f, hsA1 = 0.0f;
    const int g1 = wv / 5, q1 = wv % 5;                  // j1 = wv -> (jg, jj)
    const int g2 = (16 + wv) / 5, q2 = (16 + wv) % 5;    // j2 = 16+wv

#pragma unroll 1
    for (int tb = 0; tb < 41; ++tb) {
      const int t0 = tb * 8;
      // stage x: feats[n*128 + c*8 + dt]
#pragma unroll
      for (int it = 0; it < 2; ++it) {
        int idx = tid + it * 1024;
        if (idx < NSc * 32) {
          int n = idx >> 5, c = (idx >> 3) & 3, dt = idx & 7;
          int t = t0 + dt;
          float v = (t < Tc) ? dbase[(n + (c >> 1) * NSc) * 650 + (c & 1) * 325 + t] : 0.0f;
          feats[n * 128 + c * 8 + dt] = v;
        }
      }
      __syncthreads();
#pragma unroll
      for (int k = 1; k <= 3; ++k) {
#pragma unroll
        for (int it = 0; it < 2; ++it) {
          int idx = tid + it * 1024;
          if (idx < NSc * 32) {
            int n = idx >> 5, c = (idx >> 3) & 3, dt = idx & 7;
            float v = 0.0f;
            for (int e = roffS[n]; e < roffS[n + 1]; ++e) {
              int2 ed = edgeS[e];
              v = fmaf(__int_as_float(ed.y), feats[ed.x * 128 + ((k - 1) * 4 + c) * 8 + dt], v);
            }
            feats[n * 128 + (k * 4 + c) * 8 + dt] = v;
          }
        }
        __syncthreads();
      }
      // conv + LIF + ballot -> spkA
#pragma unroll
      for (int q = 0; q < 3; ++q) {
        if (q < nq) {
          int i = wv + 16 * q;
          float za[8];
#pragma unroll
          for (int dt = 0; dt < 8; ++dt) za[dt] = bcv;
#pragma unroll
          for (int r = 0; r < 16; ++r) {
            float4 fa = *(const float4*)&feats[i * 128 + r * 8];
            float4 fb = *(const float4*)&feats[i * 128 + r * 8 + 4];
            za[0] = fmaf(fa.x, wc[r], za[0]);
            za[1] = fmaf(fa.y, wc[r], za[1]);
            za[2] = fmaf(fa.z, wc[r], za[2]);
            za[3] = fmaf(fa.w, wc[r], za[3]);
            za[4] = fmaf(fb.x, wc[r], za[4]);
            za[5] = fmaf(fb.y, wc[r], za[5]);
            za[6] = fmaf(fb.z, wc[r], za[6]);
            za[7] = fmaf(fb.w, wc[r], za[7]);
          }
#pragma unroll
          for (int dt = 0; dt < 8; ++dt) {
            if (t0 + dt < Tc) {
              float old = cm[q];
              float m = (old * 0.2f) * ((old > 0.5f) ? 0.0f : 1.0f) + za[dt];
              cm[q] = m;
              u64 wd = __ballot(m > 0.5f);
              if (lane == 0) *(u64*)&spkA[(dt * 40 + i) * 2] = wd;
            }
          }
        }
      }
      __syncthreads();
      // fc: 2 rounds of 4 dt, register weights
#pragma unroll
      for (int r = 0; r < 2; ++r) {
        float ya[4][5];
#pragma unroll
        for (int ds = 0; ds < 4; ++ds)
#pragma unroll
          for (int jj = 0; jj < 5; ++jj) ya[ds][jj] = 0.0f;
#pragma unroll
        for (int ii = 0; ii < 10; ++ii) {
          int i = iqA * 10 + ii;     // i=39 reads zeroed pad, wfc=0
#pragma unroll
          for (int ds = 0; ds < 4; ++ds) {
            u32 wb = spkA[((r * 4 + ds) * 40 + i) * 2 + lhalf];
            float g = (float)((wb >> lbit) & 1u);
#pragma unroll
            for (int jj = 0; jj < 5; ++jj)
              ya[ds][jj] = fmaf(g, wfc[ii * 5 + jj], ya[ds][jj]);
          }
        }
#pragma unroll
        for (int off = 32; off >= 1; off >>= 1)
#pragma unroll
          for (int ds = 0; ds < 4; ++ds)
#pragma unroll
            for (int jj = 0; jj < 5; ++jj)
              ya[ds][jj] += __shfl_xor(ya[ds][jj], off, 64);
        if (lane == 0) {
#pragma unroll
          for (int ds = 0; ds < 4; ++ds)
#pragma unroll
            for (int jj = 0; jj < 5; ++jj)
              partbuf[((r * 4 + ds) * 16 + wv) * 5 + jj] = ya[ds][jj];
        }
      }
      __syncthreads();
      // h-LIF: wave wv -> j=wv (and 16+wv for wv<4)
#pragma unroll
      for (int dtt = 0; dtt < 8; ++dtt) {
        int t = t0 + dtt;
        if (t < Tc) {
          float y = partbuf[(dtt * 16 + g1 * 4 + 0) * 5 + q1]
                  + partbuf[(dtt * 16 + g1 * 4 + 1) * 5 + q1]
                  + partbuf[(dtt * 16 + g1 * 4 + 2) * 5 + q1]
                  + partbuf[(dtt * 16 + g1 * 4 + 3) * 5 + q1] + bA0;
          hmA0 = (hmA0 * 0.2f) * ((hmA0 > 0.5f) ? 0.0f : 1.0f) + y;
          hsA0 += (hmA0 > 0.5f) ? 1.0f : 0.0f;
          if (wv < 4) {
            float y2 = partbuf[(dtt * 16 + g2 * 4 + 0) * 5 + q2]
                     + partbuf[(dtt * 16 + g2 * 4 + 1) * 5 + q2]
                     + partbuf[(dtt * 16 + g2 * 4 + 2) * 5 + q2]
                     + partbuf[(dtt * 16 + g2 * 4 + 3) * 5 + q2] + bA1;
            hmA1 = (hmA1 * 0.2f) * ((hmA1 > 0.5f) ? 0.0f : 1.0f) + y2;
            hsA1 += (hmA1 > 0.5f) ? 1.0f : 0.0f;
          }
        }
      }
      __syncthreads();
    }
    if (lane == 0) {
      outS_l[wv] = hsA0 / (float)Tc;
      if (wv < 4) outS_l[16 + wv] = hsA1 / (float)Tc;
    }
  }
  __syncthreads();

  // ============ Phase B: temporal conv chain -> spike words spkT[s][i] ============
  {
    float wc[16];
#pragma unroll
    for (int r = 0; r < 16; ++r) wc[r] = c2w[r * COc + lane];
    const float bcv = c2b[lane];
    float tm[21];
#pragma unroll
    for (int q = 0; q < 21; ++q) tm[q] = 0.0f;
    const int nq = (wv < 5) ? 21 : 20;

#pragma unroll 1
    for (int s = 0; s < NSc; ++s) {
#pragma unroll
      for (int it = 0; it < 2; ++it) {
        int idx = tid + it * 1024;
        if (idx < Tc * 4) {
          int c = idx / Tc, t = idx - c * Tc;
          feats[t * 20 + c] = dbase[(s + (c >> 1) * NSc) * 650 + (c & 1) * 325 + t];
        }
      }
      __syncthreads();
#pragma unroll
      for (int k = 1; k <= 3; ++k) {
#pragma unroll
        for (int it = 0; it < 2; ++it) {
          int idx = tid + it * 1024;
          if (idx < Tc * 4) {
            int t = idx >> 2, c = idx & 3;
            float v = 0.0f;
            for (int e = roffT[t]; e < roffT[t + 1]; ++e) {
              int2 ed = edgeT[e];
              v = fmaf(__int_as_float(ed.y), feats[ed.x * 20 + (k - 1) * 4 + c], v);
            }
            feats[t * 20 + k * 4 + c] = v;
          }
        }
        __syncthreads();
      }
#pragma unroll
      for (int q = 0; q < 21; ++q) {
        if (q < nq) {
          int i = wv + 16 * q;
          float4 f0 = *(const float4*)&feats[i * 20 + 0];
          float4 f1 = *(const float4*)&feats[i * 20 + 4];
          float4 f2 = *(const float4*)&feats[i * 20 + 8];
          float4 f3 = *(const float4*)&feats[i * 20 + 12];
          float acc = bcv;
          acc = fmaf(f0.x, wc[0], acc);  acc = fmaf(f0.y, wc[1], acc);
          acc = fmaf(f0.z, wc[2], acc);  acc = fmaf(f0.w, wc[3], acc);
          acc = fmaf(f1.x, wc[4], acc);  acc = fmaf(f1.y, wc[5], acc);
          acc = fmaf(f1.z, wc[6], acc);  acc = fmaf(f1.w, wc[7], acc);
          acc = fmaf(f2.x, wc[8], acc);  acc = fmaf(f2.y, wc[9], acc);
          acc = fmaf(f2.z, wc[10], acc); acc = fmaf(f2.w, wc[11], acc);
          acc = fmaf(f3.x, wc[12], acc); acc = fmaf(f3.y, wc[13], acc);
          acc = fmaf(f3.z, wc[14], acc); acc = fmaf(f3.w, wc[15], acc);
          float old = tm[q];
          float m = (old * 0.2f) * ((old > 0.5f) ? 0.0f : 1.0f) + acc;
          tm[q] = m;
          u64 wd = __ballot(m > 0.5f);
          if (lane == 0) *(u64*)&spkT[(s * Tc + i) * 2] = wd;
        }
      }
      __syncthreads();
    }
  }

  // ============ Phase C: temporal fc, 2 passes over w2T ============
  {
    const int jgC = wv / 3;            // 0..4 (wv 0..14); wv 15 idle in GEMM
    const int iqC = wv % 3;
    const int j0C = jgC * 4;
    const int i0C = (iqC * Tc) / 3, i1C = ((iqC + 1) * Tc) / 3;
    const float* wp0 = w2T + (size_t)(j0C + 0) * (Tc * COc) + lane;
    const float* wp1 = w2T + (size_t)(j0C + 1) * (Tc * COc) + lane;
    const float* wp2 = w2T + (size_t)(j0C + 2) * (Tc * COc) + lane;
    const float* wp3 = w2T + (size_t)(j0C + 3) * (Tc * COc) + lane;
    const float bC0 = tf1b[wv < NCc ? wv : 0];
    const float bC1 = (wv < 4) ? tf1b[16 + wv] : 0.0f;
    const int gg1 = wv >> 2, qq1 = wv & 3;             // j1 = wv -> (j/4, j%4)
    const int gg2 = (16 + wv) >> 2, qq2 = (16 + wv) & 3;
    float hmC0 = 0.0f, hsC0 = 0.0f, hmC1 = 0.0f, hsC1 = 0.0f;

#pragma unroll 1
    for (int pass = 0; pass < 2; ++pass) {
      const int s0 = pass * 20;
      const int sn = pass ? 19 : 20;
      float ya[20][4];
#pragma unroll
      for (int s = 0; s < 20; ++s)
#pragma unroll
        for (int jj = 0; jj < 4; ++jj) ya[s][jj] = 0.0f;

      if (wv < 15) {
#pragma unroll 2
        for (int i = i0C; i < i1C; ++i) {
          float w0 = wp0[(size_t)i * COc];
          float w1 = wp1[(size_t)i * COc];
          float w2 = wp2[(size_t)i * COc];
          float w3 = wp3[(size_t)i * COc];
#pragma unroll
          for (int s = 0; s < 20; ++s) {
            u32 wb = spkT[((s0 + s) * Tc + i) * 2 + lhalf];
            float g = (float)((wb >> lbit) & 1u);
            ya[s][0] = fmaf(g, w0, ya[s][0]);
            ya[s][1] = fmaf(g, w1, ya[s][1]);
            ya[s][2] = fmaf(g, w2, ya[s][2]);
            ya[s][3] = fmaf(g, w3, ya[s][3]);
          }
        }
#pragma unroll
        for (int off = 32; off >= 1; off >>= 1)
#pragma unroll
          for (int s = 0; s < 20; ++s)
#pragma unroll
            for (int jj = 0; jj < 4; ++jj)
              ya[s][jj] += __shfl_xor(ya[s][jj], off, 64);
        if (lane == 0) {
#pragma unroll
          for (int s = 0; s < 20; ++s)
#pragma unroll
            for (int jj = 0; jj < 4; ++jj)
              partbuf[((jgC * 3 + iqC) * 20 + s) * 4 + jj] = ya[s][jj];
        }
      }
      __syncthreads();
      // h-LIF: wave wv -> j=wv (and 16+wv for wv<4)
#pragma unroll
      for (int s = 0; s < 20; ++s) {
        if (s < sn) {
          float y = partbuf[((gg1 * 3 + 0) * 20 + s) * 4 + qq1]
                  + partbuf[((gg1 * 3 + 1) * 20 + s) * 4 + qq1]
                  + partbuf[((gg1 * 3 + 2) * 20 + s) * 4 + qq1] + bC0;
          hmC0 = (hmC0 * 0.2f) * ((hmC0 > 0.5f) ? 0.0f : 1.0f) + y;
          hsC0 += (hmC0 > 0.5f) ? 1.0f : 0.0f;
          if (wv < 4) {
            float y2 = partbuf[((gg2 * 3 + 0) * 20 + s) * 4 + qq2]
                     + partbuf[((gg2 * 3 + 1) * 20 + s) * 4 + qq2]
                     + partbuf[((gg2 * 3 + 2) * 20 + s) * 4 + qq2] + bC1;
            hmC1 = (hmC1 * 0.2f) * ((hmC1 > 0.5f) ? 0.0f : 1.0f) + y2;
            hsC1 += (hmC1 > 0.5f) ? 1.0f : 0.0f;
          }
        }
      }
      __syncthreads();
    }
    if (lane == 0) {
      out[b * NCc + wv] = (outS_l[wv] + hsC0 / (float)NSc) * 0.5f;
      if (wv < 4)
        out[b * NCc + 16 + wv] = (outS_l[16 + wv] + hsC1 / (float)NSc) * 0.5f;
    }
  }
}

extern "C" void kernel_launch(void* const* d_in, const int* in_sizes, int n_in,
                              void* d_out, int out_size, void* d_ws, size_t ws_size,
                              hipStream_t stream) {
  const float* data = (const float*)d_in[0];
  const int*   eiS  = (const int*)d_in[1];
  const int*   eiT  = (const int*)d_in[2];
  const float* c1w  = (const float*)d_in[3];
  const float* c1b  = (const float*)d_in[4];
  const float* c2w  = (const float*)d_in[5];
  const float* c2b  = (const float*)d_in[6];
  const float* f1w  = (const float*)d_in[7];
  const float* f1b  = (const float*)d_in[8];
  const float* tf1w = (const float*)d_in[9];
  const float* tf1b = (const float*)d_in[10];
  float* out = (float*)d_out;
  int* wsI = (int*)d_ws;
  float* wsF = (float*)d_ws;

  prep_graph<<<2, 256, 0, stream>>>(eiS, eiT, wsI, wsF);
  prep_w<<<(NCc * Tc * COc + 255) / 256, 256, 0, stream>>>(f1w, wsF + WS_W1T,
                                                           tf1w, wsF + WS_W2T);
  lif_fused<<<Bc, 1024, 0, stream>>>(data,
                                     wsI + WS_ROFF_S, (const int2*)(wsI + WS_EDGE_S),
                                     wsI + WS_ROFF_T, (const int2*)(wsI + WS_EDGE_T),
                                     c1w, c1b, c2w, c2b,
                                     wsF + WS_W1T, f1b, wsF + WS_W2T, tf1b,
                                     out);
}